// Round 6
// baseline (604.642 us; speedup 1.0000x reference)
//
#include <hip/hip_runtime.h>
#include <hip/hip_bf16.h>

typedef __bf16 bf16;
typedef __attribute__((ext_vector_type(8))) __bf16 bf16x8;
typedef __attribute__((ext_vector_type(4))) float floatx4;

#define BATCH 8192
#define NREC  1024
#define DHID  2048

#define GLOBAL_AS __attribute__((address_space(1)))
#define LDS_AS    __attribute__((address_space(3)))

__device__ __forceinline__ bf16 to_bf16(float f) { return (bf16)f; }

// async global->LDS, 16 bytes per lane; LDS dest = wave-uniform base + lane*16
__device__ __forceinline__ void async16(const void* g, void* l) {
  __builtin_amdgcn_global_load_lds((const GLOBAL_AS unsigned int*)g,
                                   (LDS_AS unsigned int*)l, 16, 0, 0);
}

// raw barrier: NO implicit vmcnt drain (unlike __syncthreads) -> staged loads
// stay in flight across phase boundaries (T4). Field-tested round 3 (passed).
#define BAR()                                 \
  do {                                        \
    asm volatile("" ::: "memory");            \
    __builtin_amdgcn_s_barrier();             \
    asm volatile("" ::: "memory");            \
  } while (0)

#define VMW(N) asm volatile("s_waitcnt vmcnt(" #N ")" ::: "memory")

// ---------------- merged prep kernel (verified round 5) ----------------
__global__ __launch_bounds__(256) void prep_kernel(
    const float* __restrict__ inputs, bf16* __restrict__ A1,
    const float* __restrict__ B_re, const float* __restrict__ B_im,
    bf16* __restrict__ BreT, bf16* __restrict__ BimT,
    const float* __restrict__ C_re, const float* __restrict__ C_im,
    bf16* __restrict__ CcatT,
    const float* __restrict__ nu, const float* __restrict__ theta,
    float* __restrict__ lamRe, float* __restrict__ lamIm)
{
  __shared__ float tile[32][33];
  const int b   = blockIdx.x;
  const int tid = threadIdx.x;

  if (b < 8192) {
    const int idx = b * 256 + tid;
    float4 v = reinterpret_cast<const float4*>(inputs)[idx];
    ushort4 pk;
    pk.x = __builtin_bit_cast(unsigned short, to_bf16(v.x));
    pk.y = __builtin_bit_cast(unsigned short, to_bf16(v.y));
    pk.z = __builtin_bit_cast(unsigned short, to_bf16(v.z));
    pk.w = __builtin_bit_cast(unsigned short, to_bf16(v.w));
    *reinterpret_cast<ushort4*>(A1 + (size_t)idx * 4) = pk;
    return;
  }
  if (b < 16384) {
    const float* src; bf16* dst; int C, dstStride; float scale; int t;
    if (b < 10240)      { t = b - 8192;  src = B_re; dst = BreT;         C = 2048; dstStride = 1024; scale =  1.0f; }
    else if (b < 12288) { t = b - 10240; src = B_im; dst = BimT;         C = 2048; dstStride = 1024; scale =  1.0f; }
    else if (b < 14336) { t = b - 12288; src = C_re; dst = CcatT;        C = 1024; dstStride = 4096; scale =  1.0f; }
    else                { t = b - 14336; src = C_im; dst = CcatT + 2048; C = 1024; dstStride = 4096; scale = -1.0f; }
    const int gx = C / 32;
    const int bx = t % gx, by = t / gx;
    const int c0 = bx * 32, r0 = by * 32;
    const int tx = tid & 31, ty = tid >> 5;
    #pragma unroll
    for (int i = 0; i < 32; i += 8) {
      tile[ty + i][tx] = src[(size_t)(r0 + ty + i) * C + c0 + tx];
    }
    __syncthreads();
    #pragma unroll
    for (int i = 0; i < 32; i += 8) {
      const int c = c0 + ty + i;
      dst[(size_t)c * dstStride + r0 + tx] = to_bf16(scale * tile[tx][ty + i]);
    }
    return;
  }
  const int h = (b - 16384) * 256 + tid;
  if (h < DHID) {
    float tt = expf(-expf(nu[h]));
    lamRe[h] = tt * cosf(theta[h]);
    lamIm[h] = tt * sinf(theta[h]);
  }
}

// =====================================================================
// GEMM1 (8-phase counted-vmcnt): U_re/U_im = A @ {BreT,BimT}^T + recurrence.
// A [8192,1024]; BreT/BimT [2048,1024]. Block = 256 rows x 128 h-cols (both
// Re and Im). BK=64, 8 waves (2Mx4N), per-wave 128x32 of each of Re/Im.
// LDS: A 2x32KB + Bre 2x16KB + Bim 2x16KB = 128 KiB. Slot swizzle ^(row&7)
// on both sides (round-3 field-tested: 0 bank conflicts).
// vmcnt(4) at ph4/ph8 only -- 12 loads/thread in flight peak, never drained.
// =====================================================================

#define G1_RDA(BUF, MH)                                                        \
  {                                                                            \
    _Pragma("unroll") for (int f = 0; f < 4; ++f) {                            \
      _Pragma("unroll") for (int ks = 0; ks < 2; ++ks) {                       \
        const int row_ = wr + ((MH) * 4 + f) * 16 + m16;                       \
        aF[f][ks] = *reinterpret_cast<const bf16x8*>(                          \
            &Al[BUF][row_ * 64 + ((((ks << 2) | q) ^ (row_ & 7)) * 8)]);       \
      }                                                                        \
    }                                                                          \
  }

#define G1_RDBRE(BUF)                                                         \
  {                                                                            \
    _Pragma("unroll") for (int g = 0; g < 2; ++g) {                            \
      _Pragma("unroll") for (int ks = 0; ks < 2; ++ks) {                       \
        const int row_ = wc + g * 16 + m16;                                    \
        brF[g][ks] = *reinterpret_cast<const bf16x8*>(                         \
            &BreL[BUF][row_ * 64 + ((((ks << 2) | q) ^ (row_ & 7)) * 8)]);     \
      }                                                                        \
    }                                                                          \
  }

#define G1_RDBIM(BUF)                                                         \
  {                                                                            \
    _Pragma("unroll") for (int g = 0; g < 2; ++g) {                            \
      _Pragma("unroll") for (int ks = 0; ks < 2; ++ks) {                       \
        const int row_ = wc + g * 16 + m16;                                    \
        biF[g][ks] = *reinterpret_cast<const bf16x8*>(                         \
            &BimL[BUF][row_ * 64 + ((((ks << 2) | q) ^ (row_ & 7)) * 8)]);     \
      }                                                                        \
    }                                                                          \
  }

#define G1_MMARE(MH)                                                           \
  {                                                                            \
    __builtin_amdgcn_s_setprio(1);                                             \
    _Pragma("unroll") for (int f = 0; f < 4; ++f)                              \
      _Pragma("unroll") for (int g = 0; g < 2; ++g)                            \
        _Pragma("unroll") for (int ks = 0; ks < 2; ++ks)                       \
          accRe[(MH) * 4 + f][g] = __builtin_amdgcn_mfma_f32_16x16x32_bf16(    \
              aF[f][ks], brF[g][ks], accRe[(MH) * 4 + f][g], 0, 0, 0);         \
    __builtin_amdgcn_s_setprio(0);                                             \
  }

#define G1_MMAIM(MH)                                                           \
  {                                                                            \
    __builtin_amdgcn_s_setprio(1);                                             \
    _Pragma("unroll") for (int f = 0; f < 4; ++f)                              \
      _Pragma("unroll") for (int g = 0; g < 2; ++g)                            \
        _Pragma("unroll") for (int ks = 0; ks < 2; ++ks)                       \
          accIm[(MH) * 4 + f][g] = __builtin_amdgcn_mfma_f32_16x16x32_bf16(    \
              aF[f][ks], biF[g][ks], accIm[(MH) * 4 + f][g], 0, 0, 0);         \
    __builtin_amdgcn_s_setprio(0);                                             \
  }

__global__ __launch_bounds__(512, 2) void gemm1_kernel(
    const bf16* __restrict__ A,
    const bf16* __restrict__ BreT,
    const bf16* __restrict__ BimT,
    const float* __restrict__ state_re,
    const float* __restrict__ state_im,
    const float* __restrict__ gamma,
    const float* __restrict__ lamRe,
    const float* __restrict__ lamIm,
    float* __restrict__ xre_out,
    float* __restrict__ xim_out,
    bf16* __restrict__ Xcat)
{
  __shared__ __align__(16) bf16 Al[2][256 * 64];    // 64 KiB
  __shared__ __align__(16) bf16 BreL[2][128 * 64];  // 32 KiB
  __shared__ __align__(16) bf16 BimL[2][128 * 64];  // 32 KiB

  const int tid   = threadIdx.x;
  const int mBase = blockIdx.y * 256;
  const int hBase = blockIdx.x * 128;
  const int lane  = tid & 63;
  const int wave  = tid >> 6;            // 0..7
  const int wr    = (wave >> 2) * 128;   // 0 or 128
  const int wc    = (wave & 3) * 32;     // 0,32,64,96
  const int m16   = lane & 15;
  const int q     = lane >> 4;

  floatx4 accRe[8][2], accIm[8][2];
  #pragma unroll
  for (int i = 0; i < 8; ++i)
    #pragma unroll
    for (int g = 0; g < 2; ++g) {
      accRe[i][g] = floatx4{0.f, 0.f, 0.f, 0.f};
      accIm[i][g] = floatx4{0.f, 0.f, 0.f, 0.f};
    }

  bf16x8 aF[4][2], brF[2][2], biF[2][2];

  // A half-tile: 128 rows x 64 cols = 16 KB = 2 loads/thread
  auto stA = [&](int buf_, int kt, int half) {
    #pragma unroll
    for (int p = 0; p < 2; ++p) {
      const int pos = p * 512 + tid;
      const int r   = pos >> 3;                       // 0..127
      const int ss  = ((pos & 7) ^ (r & 7)) * 8;
      async16(&A[(size_t)(mBase + half * 128 + r) * 1024 + kt * 64 + ss],
              &Al[buf_][half * 8192 + p * 4096 + wave * 512]);
    }
  };
  // B tile: 128 rows x 64 cols = 16 KB = 2 loads/thread
  auto stBre = [&](int buf_, int kt) {
    #pragma unroll
    for (int p = 0; p < 2; ++p) {
      const int pos = p * 512 + tid;
      const int r   = pos >> 3;
      const int ss  = ((pos & 7) ^ (r & 7)) * 8;
      async16(&BreT[(size_t)(hBase + r) * 1024 + kt * 64 + ss],
              &BreL[buf_][p * 4096 + wave * 512]);
    }
  };
  auto stBim = [&](int buf_, int kt) {
    #pragma unroll
    for (int p = 0; p < 2; ++p) {
      const int pos = p * 512 + tid;
      const int r   = pos >> 3;
      const int ss  = ((pos & 7) ^ (r & 7)) * 8;
      async16(&BimT[(size_t)(hBase + r) * 1024 + kt * 64 + ss],
              &BimL[buf_][p * 4096 + wave * 512]);
    }
  };

  // prologue: tile0 (A+B) + B(1); A(1) staged in iter0 ph1/ph2
  stA(0, 0, 0); stA(0, 0, 1); stBre(0, 0); stBim(0, 0);
  stBre(1, 1);  stBim(1, 1);
  VMW(4);                               // tile0's 8 loads done; B(1) in flight
  BAR();

  // 16 K-tiles; 7 full iterations + peel (tiles 14,15)
  #pragma unroll 1
  for (int it = 0; it < 7; ++it) {
    const int t0 = 2 * it;
    // ph1
    G1_RDA(0, 0); G1_RDBRE(0); stA(1, t0 + 1, 0);
    BAR(); G1_MMARE(0); BAR();
    // ph2
    G1_RDBIM(0); stA(1, t0 + 1, 1);
    BAR(); G1_MMAIM(0); BAR();
    // ph3
    G1_RDA(0, 1); stBre(0, t0 + 2);
    BAR(); G1_MMAIM(1); BAR();
    // ph4  (in flight: B(T1)4 + A(T1)4 + Bre(T0+2)2 + Bim(T0+2)2 = 12)
    stBim(0, t0 + 2); VMW(4);
    BAR(); G1_MMARE(1); BAR();
    // ph5
    G1_RDA(1, 0); G1_RDBRE(1); stA(0, t0 + 2, 0);
    BAR(); G1_MMARE(0); BAR();
    // ph6
    G1_RDBIM(1); stA(0, t0 + 2, 1);
    BAR(); G1_MMAIM(0); BAR();
    // ph7
    G1_RDA(1, 1); stBre(1, t0 + 3);
    BAR(); G1_MMAIM(1); BAR();
    // ph8
    stBim(1, t0 + 3); VMW(4);
    BAR(); G1_MMARE(1); BAR();
  }
  // peel: tiles 14 (buf0), 15 (buf1)
  G1_RDA(0, 0); G1_RDBRE(0); stA(1, 15, 0);
  BAR(); G1_MMARE(0); BAR();
  G1_RDBIM(0); stA(1, 15, 1);
  BAR(); G1_MMAIM(0); BAR();
  G1_RDA(0, 1);
  BAR(); G1_MMAIM(1); BAR();
  VMW(0);
  BAR(); G1_MMARE(1); BAR();
  G1_RDA(1, 0); G1_RDBRE(1);
  BAR(); G1_MMARE(0); BAR();
  G1_RDBIM(1);
  BAR(); G1_MMAIM(0); BAR();
  G1_RDA(1, 1);
  BAR(); G1_MMAIM(1); BAR();
  G1_MMARE(1);

  // fused recurrence epilogue (round-5 layout: contiguous, state read once)
  #pragma unroll
  for (int g = 0; g < 2; ++g) {
    const int h  = hBase + wc + g * 16 + m16;
    const float gm = gamma[h];
    const float lr = lamRe[h];
    const float li = lamIm[h];
    #pragma unroll
    for (int i = 0; i < 8; ++i) {
      #pragma unroll
      for (int r = 0; r < 4; ++r) {
        const int row = mBase + wr + i * 16 + q * 4 + r;
        const size_t off = (size_t)row * DHID + h;
        const float ur = gm * accRe[i][g][r];
        const float ui = gm * accIm[i][g][r];
        const float sr = state_re[off];
        const float si = state_im[off];
        const float xr = sr * lr - si * li + ur;
        const float xi = sr * li + si * lr + ui;
        xre_out[off] = xr;
        xim_out[off] = xi;
        const size_t xoff = (size_t)row * (2 * DHID) + h;
        Xcat[xoff]        = to_bf16(xr);
        Xcat[xoff + DHID] = to_bf16(xi);
      }
    }
  }
}

// =====================================================================
// GEMM2 (4-phase counted-vmcnt): y = Xcat @ Ccat + D*inputs
// Xcat [8192,4096]; CcatT [1024,4096]. BM=256, BN=128 -> grid 8x32 = 256
// blocks = 1/CU. BK=64, 8 waves (2Mx4N), per-wave 128x32, acc[8][2].
// LDS: A 2x32KB + B 2x16KB = 96 KiB. vmcnt(2) at ph2/ph4.
// =====================================================================

#define G2_RDA(BUF, MH)                                                        \
  {                                                                            \
    _Pragma("unroll") for (int f = 0; f < 4; ++f) {                            \
      _Pragma("unroll") for (int ks = 0; ks < 2; ++ks) {                       \
        const int row_ = wr + ((MH) * 4 + f) * 16 + m16;                       \
        aF[f][ks] = *reinterpret_cast<const bf16x8*>(                          \
            &Al[BUF][row_ * 64 + ((((ks << 2) | q) ^ (row_ & 7)) * 8)]);       \
      }                                                                        \
    }                                                                          \
  }

#define G2_RDB(BUF)                                                            \
  {                                                                            \
    _Pragma("unroll") for (int g = 0; g < 2; ++g) {                            \
      _Pragma("unroll") for (int ks = 0; ks < 2; ++ks) {                       \
        const int row_ = wc + g * 16 + m16;                                    \
        bF[g][ks] = *reinterpret_cast<const bf16x8*>(                          \
            &Bl[BUF][row_ * 64 + ((((ks << 2) | q) ^ (row_ & 7)) * 8)]);       \
      }                                                                        \
    }                                                                          \
  }

#define G2_MMA(MH)                                                             \
  {                                                                            \
    __builtin_amdgcn_s_setprio(1);                                             \
    _Pragma("unroll") for (int f = 0; f < 4; ++f)                              \
      _Pragma("unroll") for (int g = 0; g < 2; ++g)                            \
        _Pragma("unroll") for (int ks = 0; ks < 2; ++ks)                       \
          acc[(MH) * 4 + f][g] = __builtin_amdgcn_mfma_f32_16x16x32_bf16(      \
              aF[f][ks], bF[g][ks], acc[(MH) * 4 + f][g], 0, 0, 0);            \
    __builtin_amdgcn_s_setprio(0);                                             \
  }

__global__ __launch_bounds__(512, 2) void gemm2_kernel(
    const bf16* __restrict__ Xcat,
    const bf16* __restrict__ CcatT,
    const float* __restrict__ Dvec,
    const float* __restrict__ inputs,
    float* __restrict__ y)
{
  __shared__ __align__(16) bf16 Al[2][256 * 64];   // 64 KiB
  __shared__ __align__(16) bf16 Bl[2][128 * 64];   // 32 KiB

  const int tid   = threadIdx.x;
  const int mBase = blockIdx.y * 256;
  const int nBase = blockIdx.x * 128;
  const int lane  = tid & 63;
  const int wave  = tid >> 6;
  const int wr    = (wave >> 2) * 128;
  const int wc    = (wave & 3) * 32;
  const int m16   = lane & 15;
  const int q     = lane >> 4;

  floatx4 acc[8][2];
  #pragma unroll
  for (int i = 0; i < 8; ++i)
    #pragma unroll
    for (int g = 0; g < 2; ++g) acc[i][g] = floatx4{0.f, 0.f, 0.f, 0.f};

  bf16x8 aF[4][2], bF[2][2];

  auto stA = [&](int buf_, int kt, int half) {
    #pragma unroll
    for (int p = 0; p < 2; ++p) {
      const int pos = p * 512 + tid;
      const int r   = pos >> 3;
      const int ss  = ((pos & 7) ^ (r & 7)) * 8;
      async16(&Xcat[(size_t)(mBase + half * 128 + r) * 4096 + kt * 64 + ss],
              &Al[buf_][half * 8192 + p * 4096 + wave * 512]);
    }
  };
  auto stB = [&](int buf_, int kt) {
    #pragma unroll
    for (int p = 0; p < 2; ++p) {
      const int pos = p * 512 + tid;
      const int r   = pos >> 3;
      const int ss  = ((pos & 7) ^ (r & 7)) * 8;
      async16(&CcatT[(size_t)(nBase + r) * 4096 + kt * 64 + ss],
              &Bl[buf_][p * 4096 + wave * 512]);
    }
  };

  // prologue: A(0)+B(0) + B(1)
  stA(0, 0, 0); stA(0, 0, 1); stB(0, 0);
  stB(1, 1);
  VMW(2);                               // tile0's 6 loads done; B(1) in flight
  BAR();

  // 64 K-tiles; 31 full iterations + peel (tiles 62,63)
  #pragma unroll 1
  for (int it = 0; it < 31; ++it) {
    const int t0 = 2 * it;
    // ph1
    G2_RDA(0, 0); G2_RDB(0); stA(1, t0 + 1, 0); stA(1, t0 + 1, 1);
    BAR(); G2_MMA(0); BAR();
    // ph2  (in flight: B(T1)2 + A(T1)4 + B(T2)2 = 8)
    G2_RDA(0, 1); stB(0, t0 + 2); VMW(2);
    BAR(); G2_MMA(1); BAR();
    // ph3
    G2_RDA(1, 0); G2_RDB(1); stA(0, t0 + 2, 0); stA(0, t0 + 2, 1);
    BAR(); G2_MMA(0); BAR();
    // ph4  (in flight: B(T2)2 + A(T2)4 + B(T3)2 = 8)
    G2_RDA(1, 1); stB(1, t0 + 3); VMW(2);
    BAR(); G2_MMA(1); BAR();
  }
  // peel: tiles 62 (buf0), 63 (buf1)
  G2_RDA(0, 0); G2_RDB(0); stA(1, 63, 0); stA(1, 63, 1);
  BAR(); G2_MMA(0); BAR();
  G2_RDA(0, 1); VMW(0);
  BAR(); G2_MMA(1); BAR();
  G2_RDA(1, 0); G2_RDB(1);
  BAR(); G2_MMA(0); BAR();
  G2_RDA(1, 1);
  BAR(); G2_MMA(1);

  #pragma unroll
  for (int g = 0; g < 2; ++g) {
    const int n = nBase + wc + g * 16 + m16;
    const float dv = Dvec[n];
    #pragma unroll
    for (int i = 0; i < 8; ++i) {
      #pragma unroll
      for (int r = 0; r < 4; ++r) {
        const int row = mBase + wr + i * 16 + q * 4 + r;
        const size_t idx = (size_t)row * NREC + n;
        y[idx] = acc[i][g][r] + dv * inputs[idx];
      }
    }
  }
}

// ---------------- launch ----------------

extern "C" void kernel_launch(void* const* d_in, const int* in_sizes, int n_in,
                              void* d_out, int out_size, void* d_ws, size_t ws_size,
                              hipStream_t stream) {
  (void)in_sizes; (void)n_in; (void)out_size; (void)ws_size;

  const float* inputs   = (const float*)d_in[0];
  const float* state_re = (const float*)d_in[1];
  const float* state_im = (const float*)d_in[2];
  const float* B_re     = (const float*)d_in[3];
  const float* B_im     = (const float*)d_in[4];
  const float* C_re     = (const float*)d_in[5];
  const float* C_im     = (const float*)d_in[6];
  const float* Dvec     = (const float*)d_in[7];
  const float* nu       = (const float*)d_in[8];
  const float* theta    = (const float*)d_in[9];
  const float* gamma    = (const float*)d_in[10];

  float* out     = (float*)d_out;
  float* y_out   = out;
  float* xre_out = out + (size_t)BATCH * NREC;
  float* xim_out = xre_out + (size_t)BATCH * DHID;

  char* ws = (char*)d_ws;
  bf16*  A1    = (bf16*)(ws + 0);           // 16 MB: inputs bf16 [8192,1024]
  bf16*  BreT  = (bf16*)(ws + 16777216);    // 4 MB:  [2048,1024]
  bf16*  BimT  = (bf16*)(ws + 20971520);    // 4 MB
  bf16*  CcatT = (bf16*)(ws + 25165824);    // 8 MB:  [1024,4096] = [C_re | -C_im]^T
  bf16*  Xcat  = (bf16*)(ws + 33554432);    // 64 MB: [8192,4096]
  float* lamRe = (float*)(ws + 100663296);  // 8 KB
  float* lamIm = (float*)(ws + 100671488);  // 8 KB

  prep_kernel<<<dim3(16392), dim3(256), 0, stream>>>(
      inputs, A1, B_re, B_im, BreT, BimT, C_re, C_im, CcatT,
      nu, theta, lamRe, lamIm);

  gemm1_kernel<<<dim3(DHID / 128, BATCH / 256), dim3(512), 0, stream>>>(
      A1, BreT, BimT, state_re, state_im, gamma, lamRe, lamIm, xre_out, xim_out, Xcat);

  gemm2_kernel<<<dim3(NREC / 128, BATCH / 256), dim3(512), 0, stream>>>(
      Xcat, CcatT, Dvec, inputs, y_out);
}